// Round 1
// 2519.662 us; speedup vs baseline: 1.5122x; 1.5122x over previous
//
#include <hip/hip_runtime.h>
#include <math.h>

// Sizes (fixed by the problem)
#define B_ 32
#define S_ 64
#define T_ 64
#define EMB_ 256
#define HID_ 512
#define VSZ_ 32000
#define G4_ 2048            // 4*HID

// ---------------------------------------------------------------------------
// Workspace layout (floats). Total = 15,794,176 floats = 63.2 MB.
//  xw_f   [S][B][2048] gate-interleaved (j' = (j%512)*4 + j/512)
//  xw_b   same
//  hscat  [S][B][1024]  (fwd h in [0:512], bwd h in [512:1024])
//  encout [B][S][512]
//  ctx    [B][512]
//  hdec   [64][B][512]  (slot 0 = h_init, slots 1..63 = decoder h_t)
//  cbuf   enc f/b c-state (2*16384) + dec c-state (16384)
//  wtf/wtb/wtd  [512][2048] transposed+gate-interleaved Whh
//  pre aliases xw_f (dead after encoder)
// ---------------------------------------------------------------------------
#define O_XWF    0
#define O_XWB    4194304
#define O_HSCAT  8388608
#define O_ENCOUT 10485760
#define O_CTX    11534336
#define O_HDEC   11550720
#define O_CBUF   12599296
#define O_WTF    12648448
#define O_WTB    13697024
#define O_WTD    14745600

// ---------------------------------------------------------------------------
// Transpose Whh [2048][512] -> Wt [512 k][2048 j'] with j' = (j%512)*4 + j/512
// (gate-interleaved so the 4 gate rows for one column are one float4)
// grid (64, 16, 3), block 256
// ---------------------------------------------------------------------------
__global__ __launch_bounds__(256) void k_transpose(
    const float* __restrict__ Wf, const float* __restrict__ Wb,
    const float* __restrict__ Wd,
    float* __restrict__ Of, float* __restrict__ Ob, float* __restrict__ Od)
{
    __shared__ float ld[32][33];
    const int z = blockIdx.z;
    const float* W = (z == 0) ? Wf : (z == 1) ? Wb : Wd;
    float* O = (z == 0) ? Of : (z == 1) ? Ob : Od;
    const int t = threadIdx.x;
    const int jt = blockIdx.x * 32, kt = blockIdx.y * 32;
    {
        int kl = t & 31, jl4 = t >> 5;               // 8 j-groups, 4 rows each
        #pragma unroll
        for (int jj = 0; jj < 4; ++jj) {
            int j = jl4 + jj * 8;
            ld[j][kl] = W[(size_t)(jt + j) * 512 + kt + kl];
        }
    }
    __syncthreads();
    {
        int jl = t & 31, kg = t >> 5;
        int j = jt + jl;
        int jp = ((j & 511) << 2) | (j >> 9);
        #pragma unroll
        for (int ii = 0; ii < 4; ++ii) {
            int k = kg * 4 + ii;
            O[(size_t)(kt + k) * 2048 + jp] = ld[jl][k];
        }
    }
}

// ---------------------------------------------------------------------------
// Generic tiled fp32 GEMM-TN: C[M][N] = A[M][K] * W[N][K]^T + bias, with
// mode-specific A gather and C store/activation.
// BM=BN=128, BK=16, 256 threads, 8x8 register tile.
// MODE 0: enc input proj (z = dir). A = enc_emb[src], C = xw (interleaved)
// MODE 1: enc_out + h_init.         A = hscat,        C = encout / tanh->h_init
// MODE 2: dec precompute.           A = [dec_emb[tgt], ctx], C = pre (interl.)
// MODE 3: vocab projection.         A = hdec,         C = out[b][t+1][v]
// ---------------------------------------------------------------------------
template<int MODE, int K>
__global__ __launch_bounds__(256) void k_gemm(
    const float* __restrict__ A0, const float* __restrict__ A1,
    const int*   __restrict__ I0,
    const float* __restrict__ W0, const float* __restrict__ W1,
    const float* __restrict__ bias0, const float* __restrict__ bias1,
    float* __restrict__ C0, float* __restrict__ C1, float* __restrict__ C2,
    int M)
{
    __shared__ float As[16][132];
    __shared__ float Bs[16][132];

    const int t = threadIdx.x;
    const int m0 = blockIdx.y * 128;
    const int n0 = blockIdx.x * 128;
    const int z = blockIdx.z;
    const int tm8 = (t >> 4) * 8;
    const int tn8 = (t & 15) * 8;

    const float* W    = (MODE == 0 && z == 1) ? W1 : W0;
    const float* Bp   = (MODE == 0 && z == 1) ? bias1 : bias0;
    float*       Cout = (MODE == 0 && z == 1) ? C1 : C0;

    auto loadA = [&](int r, int k) -> float4 {
        if constexpr (MODE == 0) {
            int s = r >> 5, b = r & 31;
            int id = I0[b * 64 + s];
            return *(const float4*)&A0[(size_t)id * 256 + k];
        } else if constexpr (MODE == 1) {
            if (r < 2048) {
                int b = r >> 6, s = r & 63;
                return *(const float4*)&A0[s * 32768 + b * 1024 + k];
            } else {
                int b = r - 2048;   // hT rows: fwd final = hs[63], bwd final = hs[0]
                return *(const float4*)&A0[(k < 512 ? 63 * 32768 : 0) + b * 1024 + k];
            }
        } else if constexpr (MODE == 2) {
            int tt = r >> 5, b = r & 31;
            if (k < 256) {
                int id = I0[b * 64 + tt];
                return *(const float4*)&A0[(size_t)id * 256 + k];
            } else {
                return *(const float4*)&A1[b * 512 + (k - 256)];
            }
        } else {
            return *(const float4*)&A0[(size_t)r * 512 + k];
        }
    };

    float acc[8][8];
    #pragma unroll
    for (int i = 0; i < 8; ++i)
        #pragma unroll
        for (int j = 0; j < 8; ++j) acc[i][j] = 0.f;

    for (int k0 = 0; k0 < K; k0 += 16) {
        #pragma unroll
        for (int i2 = 0; i2 < 2; ++i2) {
            int slot = t + i2 * 256;         // 512 float4 slots per tile
            int rl = slot >> 2, kq = slot & 3;
            int kk0 = k0 + kq * 4;
            float4 av = make_float4(0.f, 0.f, 0.f, 0.f);
            if (m0 + rl < M) av = loadA(m0 + rl, kk0);
            As[kq * 4 + 0][rl] = av.x; As[kq * 4 + 1][rl] = av.y;
            As[kq * 4 + 2][rl] = av.z; As[kq * 4 + 3][rl] = av.w;
            float4 bv = *(const float4*)&W[(size_t)(n0 + rl) * K + kk0];
            Bs[kq * 4 + 0][rl] = bv.x; Bs[kq * 4 + 1][rl] = bv.y;
            Bs[kq * 4 + 2][rl] = bv.z; Bs[kq * 4 + 3][rl] = bv.w;
        }
        __syncthreads();
        #pragma unroll
        for (int kk = 0; kk < 16; ++kk) {
            float a[8], b[8];
            *(float4*)&a[0] = *(const float4*)&As[kk][tm8];
            *(float4*)&a[4] = *(const float4*)&As[kk][tm8 + 4];
            *(float4*)&b[0] = *(const float4*)&Bs[kk][tn8];
            *(float4*)&b[4] = *(const float4*)&Bs[kk][tn8 + 4];
            #pragma unroll
            for (int i = 0; i < 8; ++i)
                #pragma unroll
                for (int j = 0; j < 8; ++j)
                    acc[i][j] = fmaf(a[i], b[j], acc[i][j]);
        }
        __syncthreads();
    }

    #pragma unroll
    for (int i = 0; i < 8; ++i) {
        int r = m0 + tm8 + i;
        if (r >= M) break;
        #pragma unroll
        for (int j = 0; j < 8; ++j) {
            int n = n0 + tn8 + j;
            float v = acc[i][j] + Bp[n];
            if constexpr (MODE == 0) {
                int s = r >> 5, b = r & 31;
                int np = ((n & 511) << 2) | (n >> 9);
                Cout[s * 65536 + b * 2048 + np] = v;
            } else if constexpr (MODE == 1) {
                if (r < 2048) Cout[r * 512 + n] = v;
                else          C2[(r - 2048) * 512 + n] = tanhf(v);
            } else if constexpr (MODE == 2) {
                int tt = r >> 5, b = r & 31;
                int np = ((n & 511) << 2) | (n >> 9);
                Cout[tt * 65536 + b * 2048 + np] = v;
            } else {
                int tt = r >> 5, b = r & 31;
                Cout[(size_t)b * 2048000 + (size_t)(tt + 1) * 32000 + n] = v;
            }
        }
    }
}

// ---------------------------------------------------------------------------
// One LSTM step, register-blocked + 8-way k-split.
// Block 256 threads = tile of 32 colgroups (=128 gate-cols) x 8 batches.
// Phase 1: thread (cgl, kh) accumulates 4 gates x 8 batches over k = 8j+kh
//          (each weight float4 reused for 8 batches; h broadcast from LDS).
// Phase 2: LDS reduce over the 8 k-slices; thread (cgl, b) does the
//          pointwise cell update (c in global cbuf, h to global).
// mode 0 (encoder): grid 128 blocks, dir chosen by bid&7 so fwd weights
//   live on XCDs 0-3 and bwd on 4-7 (each 4MB Whh stays L2-resident).
// mode 1 (decoder): grid 64 blocks.
// ---------------------------------------------------------------------------
__global__ __launch_bounds__(256) void k_gates(
    int mode, int i,
    const float* __restrict__ xwf, const float* __restrict__ xwb,
    const float* __restrict__ wtf, const float* __restrict__ wtb,
    float* __restrict__ hscat, float* __restrict__ hdec0,
    float* __restrict__ cbase)
{
    __shared__ float hT[512][8];        // h transposed [k][b]        16 KB
    __shared__ float red[8][8][32][4];  // [kh][b][cgl][gate]         32 KB

    const int t = threadIdx.x;
    const int bid = blockIdx.x;

    int dir, cgT, bT, zero_h, zero_c, hstr;
    const float *xw, *wt, *hsrc;
    float *hdst, *cb;
    if (mode == 0) {
        const int xcd = bid & 7;
        dir = xcd >> 2;                              // XCD 0-3 fwd, 4-7 bwd
        const int idx = ((bid >> 3) << 2) + (xcd & 3);   // 0..63 within dir
        cgT = idx & 15; bT = idx >> 4;
        const int s = dir ? (63 - i) : i;
        xw = (dir ? xwb : xwf) + s * 65536;
        wt = dir ? wtb : wtf;
        const int sp = dir ? (s + 1) : (s - 1);
        hsrc = hscat + sp * 32768 + dir * 512;
        hdst = hscat + s  * 32768 + dir * 512;
        hstr = 1024;
        cb = cbase + dir * 16384;
        zero_h = (i == 0); zero_c = (i == 0);
    } else {
        cgT = bid & 15; bT = bid >> 4;
        dir = 0;
        xw = xwf + i * 65536;
        wt = wtf;
        hsrc = hdec0 + (i - 1) * 16384;     // i=0 -> h_init slot
        hdst = hdec0 + i * 16384;
        hstr = 512;
        cb = cbase + 32768;
        zero_h = 0; zero_c = (i == 0);
    }
    const int b0  = bT * 8;
    const int cg0 = cgT * 32;

    // ---- stage h (8 batches x 512) into LDS, transposed to hT[k][b] ----
    if (!zero_h) {
        const int bb = t & 7, kq = t >> 3;          // kq in [0,32)
        #pragma unroll
        for (int j = 0; j < 4; ++j) {
            const int k = kq * 16 + j * 4;
            const float4 h4 = *(const float4*)&hsrc[(b0 + bb) * hstr + k];
            hT[k + 0][bb] = h4.x; hT[k + 1][bb] = h4.y;
            hT[k + 2][bb] = h4.z; hT[k + 3][bb] = h4.w;
        }
    }
    __syncthreads();

    // ---- phase 1: partial dot over this thread's k-slice ----
    const int cgl = t & 31, kh = t >> 5;
    const int cg = cg0 + cgl;

    float4 acc[8];
    #pragma unroll
    for (int b = 0; b < 8; ++b) acc[b] = make_float4(0.f, 0.f, 0.f, 0.f);

    if (!zero_h) {
        const float4* wt4 = (const float4*)wt;
        #pragma unroll 4
        for (int j = 0; j < 64; ++j) {
            const int k = j * 8 + kh;               // interleaved k-split
            const float4 w = wt4[(size_t)k * 512 + cg];
            float hv[8];
            *(float4*)&hv[0] = *(const float4*)&hT[k][0];
            *(float4*)&hv[4] = *(const float4*)&hT[k][4];
            #pragma unroll
            for (int b = 0; b < 8; ++b) {
                acc[b].x = fmaf(hv[b], w.x, acc[b].x);
                acc[b].y = fmaf(hv[b], w.y, acc[b].y);
                acc[b].z = fmaf(hv[b], w.z, acc[b].z);
                acc[b].w = fmaf(hv[b], w.w, acc[b].w);
            }
        }
        #pragma unroll
        for (int b = 0; b < 8; ++b)
            *(float4*)&red[kh][b][cgl][0] = acc[b];
    }
    __syncthreads();

    // ---- phase 2: reduce k-slices + pointwise cell update ----
    const int cgl2 = t & 31, bb2 = t >> 5;
    const int b_g = b0 + bb2, cg_g = cg0 + cgl2;

    float4 g = *(const float4*)&xw[b_g * 2048 + cg_g * 4];
    if (!zero_h) {
        #pragma unroll
        for (int kh2 = 0; kh2 < 8; ++kh2) {
            const float4 p = *(const float4*)&red[kh2][bb2][cgl2][0];
            g.x += p.x; g.y += p.y; g.z += p.z; g.w += p.w;
        }
    }
    const float iv = 1.f / (1.f + expf(-g.x));
    const float fv = 1.f / (1.f + expf(-g.y));
    const float gv = tanhf(g.z);
    const float ov = 1.f / (1.f + expf(-g.w));
    const float cold = zero_c ? 0.f : cb[b_g * 512 + cg_g];
    const float cn = fv * cold + iv * gv;
    cb[b_g * 512 + cg_g] = cn;
    hdst[b_g * hstr + cg_g] = ov * tanhf(cn);
}

// ---------------------------------------------------------------------------
// Attention context (constant across decoder steps! softmax over S is
// invariant to the h@w1 and attnb terms, which are constant along S).
// One block per batch row.
// ---------------------------------------------------------------------------
__global__ __launch_bounds__(256) void k_ctx(
    const float* __restrict__ encout, const float* __restrict__ attnW,
    float* __restrict__ ctx)
{
    __shared__ float red[256];
    __shared__ float sc[64];
    const int b = blockIdx.x;
    const int t = threadIdx.x;
    const float* eb = encout + b * 64 * 512;
    const float* w2 = attnW + 512;

    int s = t >> 2, part = t & 3;
    float p = 0.f;
    for (int h = part * 128; h < part * 128 + 128; ++h)
        p += eb[s * 512 + h] * w2[h];
    red[t] = p;
    __syncthreads();
    if (part == 0) sc[s] = red[t] + red[t + 1] + red[t + 2] + red[t + 3];
    __syncthreads();
    if (t == 0) {
        float mx = -1e30f;
        for (int s2 = 0; s2 < 64; ++s2) mx = fmaxf(mx, sc[s2]);
        float sum = 0.f;
        for (int s2 = 0; s2 < 64; ++s2) { sc[s2] = expf(sc[s2] - mx); sum += sc[s2]; }
        float inv = 1.f / sum;
        for (int s2 = 0; s2 < 64; ++s2) sc[s2] *= inv;
    }
    __syncthreads();
    for (int h = t; h < 512; h += 256) {
        float a = 0.f;
        for (int s2 = 0; s2 < 64; ++s2) a += sc[s2] * eb[s2 * 512 + h];
        ctx[b * 512 + h] = a;
    }
}

// Zero out[:, 0, :] (harness poisons d_out; reference has zeros at t=0)
__global__ __launch_bounds__(256) void k_zero0(float* __restrict__ out)
{
    int idx = blockIdx.x * 256 + threadIdx.x;     // float4 index, 256000 total
    int b = idx / 8000, v = idx % 8000;
    ((float4*)out)[(size_t)b * 512000 + v] = make_float4(0.f, 0.f, 0.f, 0.f);
}

// ---------------------------------------------------------------------------
extern "C" void kernel_launch(void* const* d_in, const int* in_sizes, int n_in,
                              void* d_out, int out_size, void* d_ws, size_t ws_size,
                              hipStream_t stream)
{
    const int*   src     = (const int*)  d_in[0];
    const int*   tgt     = (const int*)  d_in[1];
    const float* enc_emb = (const float*)d_in[2];
    const float* dec_emb = (const float*)d_in[3];
    const float* Wih_f   = (const float*)d_in[4];
    const float* Whh_f   = (const float*)d_in[5];
    const float* b_f     = (const float*)d_in[6];
    const float* Wih_b   = (const float*)d_in[7];
    const float* Whh_b   = (const float*)d_in[8];
    const float* b_b     = (const float*)d_in[9];
    const float* encW    = (const float*)d_in[10];
    const float* encb    = (const float*)d_in[11];
    const float* dWih    = (const float*)d_in[12];
    const float* dWhh    = (const float*)d_in[13];
    const float* db      = (const float*)d_in[14];
    const float* attnW   = (const float*)d_in[15];
    const float* projW   = (const float*)d_in[17];
    const float* projb   = (const float*)d_in[18];
    float* out = (float*)d_out;
    float* ws  = (float*)d_ws;

    float* xw_f    = ws + O_XWF;
    float* xw_b    = ws + O_XWB;
    float* hscat   = ws + O_HSCAT;
    float* encout  = ws + O_ENCOUT;
    float* ctx     = ws + O_CTX;
    float* hdec_m1 = ws + O_HDEC;         // h_init slot
    float* hdec0   = hdec_m1 + 16384;     // decoder h_t slots
    float* cb      = ws + O_CBUF;
    float* wtf     = ws + O_WTF;
    float* wtb     = ws + O_WTB;
    float* wtd     = ws + O_WTD;
    float* pre     = xw_f;                // reuse (xw_f dead after encoder)

    // 1. Transpose/interleave the three recurrent weight matrices
    k_transpose<<<dim3(64, 16, 3), 256, 0, stream>>>(Whh_f, Whh_b, dWhh, wtf, wtb, wtd);

    // 2. Encoder input projections (both directions), bias folded in
    k_gemm<0, 256><<<dim3(16, 16, 2), 256, 0, stream>>>(
        enc_emb, nullptr, src, Wih_f, Wih_b, b_f, b_b, xw_f, xw_b, nullptr, 2048);

    // 3. Bi-LSTM encoder, one launch per step (fwd + bwd concurrently)
    for (int i = 0; i < 64; ++i)
        k_gates<<<dim3(128), 256, 0, stream>>>(
            0, i, xw_f, xw_b, wtf, wtb, hscat, nullptr, cb);

    // 4. enc_out (+ h_init via tanh rows 2048..2079)
    k_gemm<1, 1024><<<dim3(4, 17, 1), 256, 0, stream>>>(
        hscat, nullptr, nullptr, encW, nullptr, encb, nullptr,
        encout, nullptr, hdec_m1, 2080);

    // 5. Attention context (constant across decoder steps)
    k_ctx<<<dim3(32), 256, 0, stream>>>(encout, attnW, ctx);

    // 6. Decoder gate precompute: [e_t, ctx] @ dWih^T + db for all 63 steps
    k_gemm<2, 768><<<dim3(16, 16, 1), 256, 0, stream>>>(
        dec_emb, ctx, tgt, dWih, nullptr, db, nullptr, pre, nullptr, nullptr, 2016);

    // 7. Decoder LSTM, one launch per step
    for (int t = 0; t < 63; ++t)
        k_gates<<<dim3(64), 256, 0, stream>>>(
            1, t, pre, nullptr, wtd, nullptr, nullptr, hdec0, cb);

    // 8. Vocab projection for all steps at once + zero t=0 slice
    k_zero0<<<dim3(1000), 256, 0, stream>>>(out);
    k_gemm<3, 512><<<dim3(250, 16, 1), 256, 0, stream>>>(
        hdec0, nullptr, nullptr, projW, nullptr, projb, nullptr,
        out, nullptr, nullptr, 2016);
}

// Round 2
// 2102.913 us; speedup vs baseline: 1.8118x; 1.1982x over previous
//
#include <hip/hip_runtime.h>
#include <math.h>

// Sizes (fixed by the problem)
#define B_ 32
#define S_ 64
#define T_ 64
#define EMB_ 256
#define HID_ 512
#define VSZ_ 32000
#define G4_ 2048            // 4*HID

typedef __attribute__((ext_vector_type(8))) short short8;
typedef __attribute__((ext_vector_type(4))) float f32x4;

// ---------------------------------------------------------------------------
// Workspace layout (floats). Total = 15,794,176 floats = 63.2 MB.
//  xw_f   [S][B][2048] gate-interleaved (j' = (j%512)*4 + j/512)
//  xw_b   same
//  hscat  [S][B][1024]  (fwd h in [0:512], bwd h in [512:1024])
//  encout [B][S][512]
//  ctx    [B][512]
//  hdec   [64][B][512]  (slot 0 = h_init, slots 1..63 = decoder h_t)
//  cbuf   enc f/b c-state (2*16384) + dec c-state (16384)
//  wtf/wtb/wtd  [512][2048] transposed+gate-interleaved Whh
//  pre aliases xw_f (dead after encoder)
// Vocab stage (after decoder, xw/hscat dead):
//  Whi/Wlo bf16 chunk planes alias xw_f/xw_b; Ahi/Alo alias hscat.
// ---------------------------------------------------------------------------
#define O_XWF    0
#define O_XWB    4194304
#define O_HSCAT  8388608
#define O_ENCOUT 10485760
#define O_CTX    11534336
#define O_HDEC   11550720
#define O_CBUF   12599296
#define O_WTF    12648448
#define O_WTB    13697024
#define O_WTD    14745600

// bf16 round-to-nearest-even helpers
__device__ __forceinline__ unsigned short f2bf(float x) {
    unsigned int u = __float_as_uint(x);
    u = (u + 0x7fffu + ((u >> 16) & 1u)) >> 16;
    return (unsigned short)u;
}
__device__ __forceinline__ float bf2f(unsigned short h) {
    return __uint_as_float(((unsigned int)h) << 16);
}

// ---------------------------------------------------------------------------
// Transpose Whh [2048][512] -> Wt [512 k][2048 j'] with j' = (j%512)*4 + j/512
// ---------------------------------------------------------------------------
__global__ __launch_bounds__(256) void k_transpose(
    const float* __restrict__ Wf, const float* __restrict__ Wb,
    const float* __restrict__ Wd,
    float* __restrict__ Of, float* __restrict__ Ob, float* __restrict__ Od)
{
    __shared__ float ld[32][33];
    const int z = blockIdx.z;
    const float* W = (z == 0) ? Wf : (z == 1) ? Wb : Wd;
    float* O = (z == 0) ? Of : (z == 1) ? Ob : Od;
    const int t = threadIdx.x;
    const int jt = blockIdx.x * 32, kt = blockIdx.y * 32;
    {
        int kl = t & 31, jl4 = t >> 5;
        #pragma unroll
        for (int jj = 0; jj < 4; ++jj) {
            int j = jl4 + jj * 8;
            ld[j][kl] = W[(size_t)(jt + j) * 512 + kt + kl];
        }
    }
    __syncthreads();
    {
        int jl = t & 31, kg = t >> 5;
        int j = jt + jl;
        int jp = ((j & 511) << 2) | (j >> 9);
        #pragma unroll
        for (int ii = 0; ii < 4; ++ii) {
            int k = kg * 4 + ii;
            O[(size_t)(kt + k) * 2048 + jp] = ld[jl][k];
        }
    }
}

// ---------------------------------------------------------------------------
// Generic tiled fp32 GEMM-TN (modes 0/1/2 — small GEMMs only now).
// ---------------------------------------------------------------------------
template<int MODE, int K>
__global__ __launch_bounds__(256) void k_gemm(
    const float* __restrict__ A0, const float* __restrict__ A1,
    const int*   __restrict__ I0,
    const float* __restrict__ W0, const float* __restrict__ W1,
    const float* __restrict__ bias0, const float* __restrict__ bias1,
    float* __restrict__ C0, float* __restrict__ C1, float* __restrict__ C2,
    int M)
{
    __shared__ float As[16][132];
    __shared__ float Bs[16][132];

    const int t = threadIdx.x;
    const int m0 = blockIdx.y * 128;
    const int n0 = blockIdx.x * 128;
    const int z = blockIdx.z;
    const int tm8 = (t >> 4) * 8;
    const int tn8 = (t & 15) * 8;

    const float* W    = (MODE == 0 && z == 1) ? W1 : W0;
    const float* Bp   = (MODE == 0 && z == 1) ? bias1 : bias0;
    float*       Cout = (MODE == 0 && z == 1) ? C1 : C0;

    auto loadA = [&](int r, int k) -> float4 {
        if constexpr (MODE == 0) {
            int s = r >> 5, b = r & 31;
            int id = I0[b * 64 + s];
            return *(const float4*)&A0[(size_t)id * 256 + k];
        } else if constexpr (MODE == 1) {
            if (r < 2048) {
                int b = r >> 6, s = r & 63;
                return *(const float4*)&A0[s * 32768 + b * 1024 + k];
            } else {
                int b = r - 2048;
                return *(const float4*)&A0[(k < 512 ? 63 * 32768 : 0) + b * 1024 + k];
            }
        } else {
            int tt = r >> 5, b = r & 31;
            if (k < 256) {
                int id = I0[b * 64 + tt];
                return *(const float4*)&A0[(size_t)id * 256 + k];
            } else {
                return *(const float4*)&A1[b * 512 + (k - 256)];
            }
        }
    };

    float acc[8][8];
    #pragma unroll
    for (int i = 0; i < 8; ++i)
        #pragma unroll
        for (int j = 0; j < 8; ++j) acc[i][j] = 0.f;

    for (int k0 = 0; k0 < K; k0 += 16) {
        #pragma unroll
        for (int i2 = 0; i2 < 2; ++i2) {
            int slot = t + i2 * 256;
            int rl = slot >> 2, kq = slot & 3;
            int kk0 = k0 + kq * 4;
            float4 av = make_float4(0.f, 0.f, 0.f, 0.f);
            if (m0 + rl < M) av = loadA(m0 + rl, kk0);
            As[kq * 4 + 0][rl] = av.x; As[kq * 4 + 1][rl] = av.y;
            As[kq * 4 + 2][rl] = av.z; As[kq * 4 + 3][rl] = av.w;
            float4 bv = *(const float4*)&W[(size_t)(n0 + rl) * K + kk0];
            Bs[kq * 4 + 0][rl] = bv.x; Bs[kq * 4 + 1][rl] = bv.y;
            Bs[kq * 4 + 2][rl] = bv.z; Bs[kq * 4 + 3][rl] = bv.w;
        }
        __syncthreads();
        #pragma unroll
        for (int kk = 0; kk < 16; ++kk) {
            float a[8], b[8];
            *(float4*)&a[0] = *(const float4*)&As[kk][tm8];
            *(float4*)&a[4] = *(const float4*)&As[kk][tm8 + 4];
            *(float4*)&b[0] = *(const float4*)&Bs[kk][tn8];
            *(float4*)&b[4] = *(const float4*)&Bs[kk][tn8 + 4];
            #pragma unroll
            for (int i = 0; i < 8; ++i)
                #pragma unroll
                for (int j = 0; j < 8; ++j)
                    acc[i][j] = fmaf(a[i], b[j], acc[i][j]);
        }
        __syncthreads();
    }

    #pragma unroll
    for (int i = 0; i < 8; ++i) {
        int r = m0 + tm8 + i;
        if (r >= M) break;
        #pragma unroll
        for (int j = 0; j < 8; ++j) {
            int n = n0 + tn8 + j;
            float v = acc[i][j] + Bp[n];
            if constexpr (MODE == 0) {
                int s = r >> 5, b = r & 31;
                int np = ((n & 511) << 2) | (n >> 9);
                Cout[s * 65536 + b * 2048 + np] = v;
            } else if constexpr (MODE == 1) {
                if (r < 2048) Cout[r * 512 + n] = v;
                else          C2[(r - 2048) * 512 + n] = tanhf(v);
            } else {
                int tt = r >> 5, b = r & 31;
                int np = ((n & 511) << 2) | (n >> 9);
                Cout[tt * 65536 + b * 2048 + np] = v;
            }
        }
    }
}

// ---------------------------------------------------------------------------
// One LSTM step, register-blocked + 8-way k-split (unchanged from R1).
// ---------------------------------------------------------------------------
__global__ __launch_bounds__(256) void k_gates(
    int mode, int i,
    const float* __restrict__ xwf, const float* __restrict__ xwb,
    const float* __restrict__ wtf, const float* __restrict__ wtb,
    float* __restrict__ hscat, float* __restrict__ hdec0,
    float* __restrict__ cbase)
{
    __shared__ float hT[512][8];
    __shared__ float red[8][8][32][4];

    const int t = threadIdx.x;
    const int bid = blockIdx.x;

    int dir, cgT, bT, zero_h, zero_c, hstr;
    const float *xw, *wt, *hsrc;
    float *hdst, *cb;
    if (mode == 0) {
        const int xcd = bid & 7;
        dir = xcd >> 2;
        const int idx = ((bid >> 3) << 2) + (xcd & 3);
        cgT = idx & 15; bT = idx >> 4;
        const int s = dir ? (63 - i) : i;
        xw = (dir ? xwb : xwf) + s * 65536;
        wt = dir ? wtb : wtf;
        const int sp = dir ? (s + 1) : (s - 1);
        hsrc = hscat + sp * 32768 + dir * 512;
        hdst = hscat + s  * 32768 + dir * 512;
        hstr = 1024;
        cb = cbase + dir * 16384;
        zero_h = (i == 0); zero_c = (i == 0);
    } else {
        cgT = bid & 15; bT = bid >> 4;
        dir = 0;
        xw = xwf + i * 65536;
        wt = wtf;
        hsrc = hdec0 + (i - 1) * 16384;
        hdst = hdec0 + i * 16384;
        hstr = 512;
        cb = cbase + 32768;
        zero_h = 0; zero_c = (i == 0);
    }
    const int b0  = bT * 8;
    const int cg0 = cgT * 32;

    if (!zero_h) {
        const int bb = t & 7, kq = t >> 3;
        #pragma unroll
        for (int j = 0; j < 4; ++j) {
            const int k = kq * 16 + j * 4;
            const float4 h4 = *(const float4*)&hsrc[(b0 + bb) * hstr + k];
            hT[k + 0][bb] = h4.x; hT[k + 1][bb] = h4.y;
            hT[k + 2][bb] = h4.z; hT[k + 3][bb] = h4.w;
        }
    }
    __syncthreads();

    const int cgl = t & 31, kh = t >> 5;
    const int cg = cg0 + cgl;

    float4 acc[8];
    #pragma unroll
    for (int b = 0; b < 8; ++b) acc[b] = make_float4(0.f, 0.f, 0.f, 0.f);

    if (!zero_h) {
        const float4* wt4 = (const float4*)wt;
        #pragma unroll 4
        for (int j = 0; j < 64; ++j) {
            const int k = j * 8 + kh;
            const float4 w = wt4[(size_t)k * 512 + cg];
            float hv[8];
            *(float4*)&hv[0] = *(const float4*)&hT[k][0];
            *(float4*)&hv[4] = *(const float4*)&hT[k][4];
            #pragma unroll
            for (int b = 0; b < 8; ++b) {
                acc[b].x = fmaf(hv[b], w.x, acc[b].x);
                acc[b].y = fmaf(hv[b], w.y, acc[b].y);
                acc[b].z = fmaf(hv[b], w.z, acc[b].z);
                acc[b].w = fmaf(hv[b], w.w, acc[b].w);
            }
        }
        #pragma unroll
        for (int b = 0; b < 8; ++b)
            *(float4*)&red[kh][b][cgl][0] = acc[b];
    }
    __syncthreads();

    const int cgl2 = t & 31, bb2 = t >> 5;
    const int b_g = b0 + bb2, cg_g = cg0 + cgl2;

    float4 g = *(const float4*)&xw[b_g * 2048 + cg_g * 4];
    if (!zero_h) {
        #pragma unroll
        for (int kh2 = 0; kh2 < 8; ++kh2) {
            const float4 p = *(const float4*)&red[kh2][bb2][cgl2][0];
            g.x += p.x; g.y += p.y; g.z += p.z; g.w += p.w;
        }
    }
    const float iv = 1.f / (1.f + expf(-g.x));
    const float fv = 1.f / (1.f + expf(-g.y));
    const float gv = tanhf(g.z);
    const float ov = 1.f / (1.f + expf(-g.w));
    const float cold = zero_c ? 0.f : cb[b_g * 512 + cg_g];
    const float cn = fv * cold + iv * gv;
    cb[b_g * 512 + cg_g] = cn;
    hdst[b_g * hstr + cg_g] = ov * tanhf(cn);
}

// ---------------------------------------------------------------------------
// Attention context (constant across decoder steps).
// ---------------------------------------------------------------------------
__global__ __launch_bounds__(256) void k_ctx(
    const float* __restrict__ encout, const float* __restrict__ attnW,
    float* __restrict__ ctx)
{
    __shared__ float red[256];
    __shared__ float sc[64];
    const int b = blockIdx.x;
    const int t = threadIdx.x;
    const float* eb = encout + b * 64 * 512;
    const float* w2 = attnW + 512;

    int s = t >> 2, part = t & 3;
    float p = 0.f;
    for (int h = part * 128; h < part * 128 + 128; ++h)
        p += eb[s * 512 + h] * w2[h];
    red[t] = p;
    __syncthreads();
    if (part == 0) sc[s] = red[t] + red[t + 1] + red[t + 2] + red[t + 3];
    __syncthreads();
    if (t == 0) {
        float mx = -1e30f;
        for (int s2 = 0; s2 < 64; ++s2) mx = fmaxf(mx, sc[s2]);
        float sum = 0.f;
        for (int s2 = 0; s2 < 64; ++s2) { sc[s2] = expf(sc[s2] - mx); sum += sc[s2]; }
        float inv = 1.f / sum;
        for (int s2 = 0; s2 < 64; ++s2) sc[s2] *= inv;
    }
    __syncthreads();
    for (int h = t; h < 512; h += 256) {
        float a = 0.f;
        for (int s2 = 0; s2 < 64; ++s2) a += sc[s2] * eb[s2 * 512 + h];
        ctx[b * 512 + h] = a;
    }
}

// Zero out[:, 0, :]
__global__ __launch_bounds__(256) void k_zero0(float* __restrict__ out)
{
    int idx = blockIdx.x * 256 + threadIdx.x;
    int b = idx / 8000, v = idx % 8000;
    ((float4*)out)[(size_t)b * 512000 + v] = make_float4(0.f, 0.f, 0.f, 0.f);
}

// ---------------------------------------------------------------------------
// fp32 -> bf16 hi/lo plane split (RNE).  n4 = #float4 elements.
// ---------------------------------------------------------------------------
__global__ __launch_bounds__(256) void k_cvt(
    const float* __restrict__ X, unsigned short* __restrict__ hi,
    unsigned short* __restrict__ lo, int n4)
{
    int i = blockIdx.x * 256 + threadIdx.x;
    if (i >= n4) return;
    float4 v = ((const float4*)X)[i];
    ushort4 h, l;
    h.x = f2bf(v.x); l.x = f2bf(v.x - bf2f(h.x));
    h.y = f2bf(v.y); l.y = f2bf(v.y - bf2f(h.y));
    h.z = f2bf(v.z); l.z = f2bf(v.z - bf2f(h.z));
    h.w = f2bf(v.w); l.w = f2bf(v.w - bf2f(h.w));
    ((ushort4*)hi)[i] = h;
    ((ushort4*)lo)[i] = l;
}

// ---------------------------------------------------------------------------
// Vocab projection via bf16x3-split MFMA (hi*hi + hi*lo + lo*hi ~= fp32).
// C[2016][16000-chunk] = A[2016][512] * W[16000][512]^T + bias.
// Tile 128x128, BK=64, 256 threads (2x2 waves of 64x64).
// LDS tiles stored in FRAG ORDER: 16B slot per (frag, ksub, lane) ->
// lane-linear ds_read_b128 / ds_write_b128, conflict-free.
// Frag layout (16x16x32 bf16): A[m0+(l&15)][ks*32+(l>>4)*8 +j],
//                              B=W[n0+(l&15)][same k] (verified m89 mapping).
// C/D: n = l&15, m = (l>>4)*4 + reg.
// ---------------------------------------------------------------------------
__global__ __launch_bounds__(256, 2) void k_vmfma(
    const unsigned short* __restrict__ Ahi, const unsigned short* __restrict__ Alo,
    const unsigned short* __restrict__ Whi, const unsigned short* __restrict__ Wlo,
    const float* __restrict__ bias, float* __restrict__ out, int n_base)
{
    __shared__ unsigned short Ah[128 * 64], Al[128 * 64];   // 16 KB each
    __shared__ unsigned short Bh[128 * 64], Bl[128 * 64];   // 64 KB total

    const int t  = threadIdx.x;
    const int m0 = blockIdx.y * 128;
    const int n0 = blockIdx.x * 128;
    const int l  = t & 63, w = t >> 6;
    const int wm = w >> 1, wn = w & 1;

    const int jj = t & 7;     // k-octet within BK=64
    const int rl = t >> 3;    // row 0..31 (4 rows per thread, stride 32)

    f32x4 acc[4][4];
    #pragma unroll
    for (int mi = 0; mi < 4; ++mi)
        #pragma unroll
        for (int ni = 0; ni < 4; ++ni)
            acc[mi][ni] = (f32x4)0.f;

    const short8 zero8 = (short8)0;

    for (int kt = 0; kt < 8; ++kt) {
        const int k0 = kt * 64;
        // ---- stage tiles in frag order ----
        #pragma unroll
        for (int i = 0; i < 4; ++i) {
            const int row  = rl + 32 * i;
            const int lane = (jj & 3) * 16 + (row & 15);
            const int slot = ((row >> 4) * 2 + (jj >> 2)) * 64 + lane;
            const size_t goff = (size_t)k0 + jj * 8;

            const int am = m0 + row;
            short8 va = zero8, vb = zero8;
            if (am < 2016) {
                va = *(const short8*)&Ahi[(size_t)am * 512 + goff];
                vb = *(const short8*)&Alo[(size_t)am * 512 + goff];
            }
            *(short8*)&Ah[slot * 8] = va;
            *(short8*)&Al[slot * 8] = vb;

            const int bn = n0 + row;
            *(short8*)&Bh[slot * 8] = *(const short8*)&Whi[(size_t)bn * 512 + goff];
            *(short8*)&Bl[slot * 8] = *(const short8*)&Wlo[(size_t)bn * 512 + goff];
        }
        __syncthreads();

        // ---- compute ----
        #pragma unroll
        for (int s = 0; s < 2; ++s) {
            short8 ah[4], al[4];
            #pragma unroll
            for (int mi = 0; mi < 4; ++mi) {
                const int slot = ((wm * 4 + mi) * 2 + s) * 64 + l;
                ah[mi] = *(const short8*)&Ah[slot * 8];
                al[mi] = *(const short8*)&Al[slot * 8];
            }
            #pragma unroll
            for (int ni = 0; ni < 4; ++ni) {
                const int slot = ((wn * 4 + ni) * 2 + s) * 64 + l;
                const short8 bh = *(const short8*)&Bh[slot * 8];
                const short8 bl = *(const short8*)&Bl[slot * 8];
                #pragma unroll
                for (int mi = 0; mi < 4; ++mi) {
                    acc[mi][ni] = __builtin_amdgcn_mfma_f32_16x16x32_bf16(ah[mi], bh, acc[mi][ni], 0, 0, 0);
                    acc[mi][ni] = __builtin_amdgcn_mfma_f32_16x16x32_bf16(ah[mi], bl, acc[mi][ni], 0, 0, 0);
                    acc[mi][ni] = __builtin_amdgcn_mfma_f32_16x16x32_bf16(al[mi], bh, acc[mi][ni], 0, 0, 0);
                }
            }
        }
        __syncthreads();
    }

    // ---- epilogue: D lane mapping n = l&15, m = (l>>4)*4 + r ----
    #pragma unroll
    for (int ni = 0; ni < 4; ++ni) {
        const int n = n0 + wn * 64 + ni * 16 + (l & 15);
        const int v = n_base + n;
        const float bv = bias[v];
        #pragma unroll
        for (int mi = 0; mi < 4; ++mi) {
            const int mbase = m0 + wm * 64 + mi * 16 + ((l >> 4) << 2);
            #pragma unroll
            for (int r = 0; r < 4; ++r) {
                const int m = mbase + r;
                if (m < 2016) {
                    const int tt = m >> 5, b = m & 31;
                    out[(size_t)b * 2048000 + (size_t)(tt + 1) * 32000 + v] =
                        acc[mi][ni][r] + bv;
                }
            }
        }
    }
}

// ---------------------------------------------------------------------------
extern "C" void kernel_launch(void* const* d_in, const int* in_sizes, int n_in,
                              void* d_out, int out_size, void* d_ws, size_t ws_size,
                              hipStream_t stream)
{
    const int*   src     = (const int*)  d_in[0];
    const int*   tgt     = (const int*)  d_in[1];
    const float* enc_emb = (const float*)d_in[2];
    const float* dec_emb = (const float*)d_in[3];
    const float* Wih_f   = (const float*)d_in[4];
    const float* Whh_f   = (const float*)d_in[5];
    const float* b_f     = (const float*)d_in[6];
    const float* Wih_b   = (const float*)d_in[7];
    const float* Whh_b   = (const float*)d_in[8];
    const float* b_b     = (const float*)d_in[9];
    const float* encW    = (const float*)d_in[10];
    const float* encb    = (const float*)d_in[11];
    const float* dWih    = (const float*)d_in[12];
    const float* dWhh    = (const float*)d_in[13];
    const float* db      = (const float*)d_in[14];
    const float* attnW   = (const float*)d_in[15];
    const float* projW   = (const float*)d_in[17];
    const float* projb   = (const float*)d_in[18];
    float* out = (float*)d_out;
    float* ws  = (float*)d_ws;

    float* xw_f    = ws + O_XWF;
    float* xw_b    = ws + O_XWB;
    float* hscat   = ws + O_HSCAT;
    float* encout  = ws + O_ENCOUT;
    float* ctx     = ws + O_CTX;
    float* hdec_m1 = ws + O_HDEC;         // h_init slot
    float* hdec0   = hdec_m1 + 16384;     // decoder h_t slots
    float* cb      = ws + O_CBUF;
    float* wtf     = ws + O_WTF;
    float* wtb     = ws + O_WTB;
    float* wtd     = ws + O_WTD;
    float* pre     = xw_f;                // reuse (xw_f dead after encoder)

    // Vocab-stage aliases (xw_f/xw_b/hscat dead after decoder loop)
    unsigned short* Whi = (unsigned short*)(ws + O_XWF);      // 16.4 MB
    unsigned short* Wlo = (unsigned short*)(ws + O_XWB);      // 16.4 MB
    unsigned short* Ahi = (unsigned short*)(ws + O_HSCAT);    // 2 MB
    unsigned short* Alo = (unsigned short*)(ws + O_HSCAT + 524288);

    // 1. Transpose/interleave the three recurrent weight matrices
    k_transpose<<<dim3(64, 16, 3), 256, 0, stream>>>(Whh_f, Whh_b, dWhh, wtf, wtb, wtd);

    // 2. Encoder input projections (both directions), bias folded in
    k_gemm<0, 256><<<dim3(16, 16, 2), 256, 0, stream>>>(
        enc_emb, nullptr, src, Wih_f, Wih_b, b_f, b_b, xw_f, xw_b, nullptr, 2048);

    // 3. Bi-LSTM encoder, one launch per step (fwd + bwd concurrently)
    for (int i = 0; i < 64; ++i)
        k_gates<<<dim3(128), 256, 0, stream>>>(
            0, i, xw_f, xw_b, wtf, wtb, hscat, nullptr, cb);

    // 4. enc_out (+ h_init via tanh rows 2048..2079)
    k_gemm<1, 1024><<<dim3(4, 17, 1), 256, 0, stream>>>(
        hscat, nullptr, nullptr, encW, nullptr, encb, nullptr,
        encout, nullptr, hdec_m1, 2080);

    // 5. Attention context (constant across decoder steps)
    k_ctx<<<dim3(32), 256, 0, stream>>>(encout, attnW, ctx);

    // 6. Decoder gate precompute: [e_t, ctx] @ dWih^T + db for all 63 steps
    k_gemm<2, 768><<<dim3(16, 16, 1), 256, 0, stream>>>(
        dec_emb, ctx, tgt, dWih, nullptr, db, nullptr, pre, nullptr, nullptr, 2016);

    // 7. Decoder LSTM, one launch per step
    for (int t = 0; t < 63; ++t)
        k_gates<<<dim3(64), 256, 0, stream>>>(
            1, t, pre, nullptr, wtd, nullptr, nullptr, hdec0, cb);

    // 8. Vocab projection: bf16x3-split MFMA, W converted in 2 chunks
    k_zero0<<<dim3(1000), 256, 0, stream>>>(out);
    k_cvt<<<dim3(1008), 256, 0, stream>>>(hdec0, Ahi, Alo, 258048);
    for (int c = 0; c < 2; ++c) {
        k_cvt<<<dim3(8000), 256, 0, stream>>>(
            projW + (size_t)c * 16000 * 512, Whi, Wlo, 2048000);
        k_vmfma<<<dim3(125, 16), 256, 0, stream>>>(
            Ahi, Alo, Whi, Wlo, projb, out, c * 16000);
    }
}